// Round 3
// baseline (415.802 us; speedup 1.0000x reference)
//
#include <hip/hip_runtime.h>
#include <math.h>

#define L_  12
#define B_  32
#define H_  12
#define N1_ 197
#define D_  768
#define HD_ 64
#define R_  19

#define KV_GEMM_BLOCKS 600            // 50 x 12 tiles of the fused K/V projection
#define K1_BLOCKS      (L_ * B_ * N1_ / 4)   // 18912

typedef __attribute__((ext_vector_type(8))) short short8;
typedef __attribute__((ext_vector_type(4))) float f32x4;

// ---------------------------------------------------------------------------
// f32 -> bf16 hi/lo split (in-register). hi = rn(f), lo = rn(f - hi).
// hi*hi + hi*lo + lo*hi reproduces the f32 product to ~2^-17 relative.
// ---------------------------------------------------------------------------
__device__ inline ushort f2bf_rn(float f) {
  unsigned u = __float_as_uint(f);
  unsigned r = (u + 0x7FFFu + ((u >> 16) & 1u)) >> 16;
  return (ushort)r;
}
__device__ inline float bf2f(ushort h) { return __uint_as_float((unsigned)h << 16); }
__device__ inline void cvt4(float4 f, ushort4& h, ushort4& l) {
  h.x = f2bf_rn(f.x); l.x = f2bf_rn(f.x - bf2f(h.x));
  h.y = f2bf_rn(f.y); l.y = f2bf_rn(f.y - bf2f(h.y));
  h.z = f2bf_rn(f.z); l.z = f2bf_rn(f.z - bf2f(h.z));
  h.w = f2bf_rn(f.w); l.w = f2bf_rn(f.w - bf2f(h.w));
}

// ---------------------------------------------------------------------------
// Split-bf16 MFMA GEMM body, f32 inputs converted in-register at staging.
// C[m,n] = sum_k A[row(m),k] * W[n,k] (+bias[n]);  row(m)=gidx?gidx[m]:m;
// W row n = n<nsplit ? W0[n] : W1[n-nsplit].
// BK=32, 256 threads = 4 waves (2x2). mfma_f32_16x16x32_bf16:
//   A/B frag: row = lane&15, k = 8*(lane>>4)+j  (contiguous -> ds_read_b128)
//   C/D:      col = lane&15, row = 4*(lane>>4)+reg      [m89-verified, R2-passed]
// LDS row stride 40 bf16 (80B): fragment reads 2-way bank aliasing = free (m136).
// ---------------------------------------------------------------------------
#define PK 40
template <int BM, int BN, int MF, int NF>
__device__ __forceinline__ void gemm_body(int bm, int bn,
                                          const float* __restrict__ A,
                                          const int* __restrict__ gidx,
                                          const float* __restrict__ W0,
                                          const float* __restrict__ W1,
                                          int nsplit,
                                          const float* __restrict__ bias,
                                          float* __restrict__ C,
                                          int M, int K, int ldc) {
  __shared__ __attribute__((aligned(16))) ushort As[2][BM][PK];
  __shared__ __attribute__((aligned(16))) ushort Bs[2][BN][PK];
  constexpr int TPRA = 256 / BM;   // threads per A row
  constexpr int EPTA = 32 / TPRA;  // f32 elems per thread per tile
  constexpr int NA4  = EPTA / 4;   // float4 loads
  constexpr int TPRB = 256 / BN;
  constexpr int EPTB = 32 / TPRB;
  constexpr int NB4  = EPTB / 4;

  int tid  = threadIdx.x;
  int lane = tid & 63, wid = tid >> 6;
  int wr = wid >> 1, wc = wid & 1;
  int lr = lane & 15, lk = lane >> 4;

  int arow_s = tid / TPRA;
  int akoff  = (tid % TPRA) * EPTA;
  int ar = bm * BM + arow_s; if (ar >= M) ar = M - 1;
  int asrc = gidx ? gidx[ar] : ar;
  const float* ap = A + (size_t)asrc * K + akoff;

  int brow_s = tid / TPRB;
  int bkoff  = (tid % TPRB) * EPTB;
  int wrow   = bn * BN + brow_s;
  const float* wp = ((wrow < nsplit) ? (W0 + (size_t)wrow * K)
                                     : (W1 + (size_t)(wrow - nsplit) * K)) + bkoff;

  f32x4 acc[MF][NF] = {};

  float4 pa[NA4], pb[NB4];
#pragma unroll
  for (int u = 0; u < NA4; ++u) pa[u] = *(const float4*)(ap + u * 4);
#pragma unroll
  for (int u = 0; u < NB4; ++u) pb[u] = *(const float4*)(wp + u * 4);

  for (int k0 = 0; k0 < K; k0 += 32) {
#pragma unroll
    for (int u = 0; u < NA4; ++u) {
      ushort4 h, l; cvt4(pa[u], h, l);
      *(ushort4*)&As[0][arow_s][akoff + u * 4] = h;
      *(ushort4*)&As[1][arow_s][akoff + u * 4] = l;
    }
#pragma unroll
    for (int u = 0; u < NB4; ++u) {
      ushort4 h, l; cvt4(pb[u], h, l);
      *(ushort4*)&Bs[0][brow_s][bkoff + u * 4] = h;
      *(ushort4*)&Bs[1][brow_s][bkoff + u * 4] = l;
    }
    __syncthreads();

    int kn = k0 + 32;
    if (kn < K) {
#pragma unroll
      for (int u = 0; u < NA4; ++u) pa[u] = *(const float4*)(ap + kn + u * 4);
#pragma unroll
      for (int u = 0; u < NB4; ++u) pb[u] = *(const float4*)(wp + kn + u * 4);
    }

    short8 af[2][MF], bf[2][NF];
#pragma unroll
    for (int m = 0; m < MF; ++m) {
      af[0][m] = *(const short8*)&As[0][wr * (BM / 2) + m * 16 + lr][lk * 8];
      af[1][m] = *(const short8*)&As[1][wr * (BM / 2) + m * 16 + lr][lk * 8];
    }
#pragma unroll
    for (int n = 0; n < NF; ++n) {
      bf[0][n] = *(const short8*)&Bs[0][wc * (BN / 2) + n * 16 + lr][lk * 8];
      bf[1][n] = *(const short8*)&Bs[1][wc * (BN / 2) + n * 16 + lr][lk * 8];
    }
#pragma unroll
    for (int m = 0; m < MF; ++m)
#pragma unroll
      for (int n = 0; n < NF; ++n) {
        acc[m][n] = __builtin_amdgcn_mfma_f32_16x16x32_bf16(af[0][m], bf[0][n], acc[m][n], 0, 0, 0);
        acc[m][n] = __builtin_amdgcn_mfma_f32_16x16x32_bf16(af[0][m], bf[1][n], acc[m][n], 0, 0, 0);
        acc[m][n] = __builtin_amdgcn_mfma_f32_16x16x32_bf16(af[1][m], bf[0][n], acc[m][n], 0, 0, 0);
      }
    __syncthreads();
  }

#pragma unroll
  for (int m = 0; m < MF; ++m) {
    int row0 = bm * BM + wr * (BM / 2) + m * 16 + lk * 4;
#pragma unroll
    for (int i = 0; i < 4; ++i) {
      int row = row0 + i;
      if (row < M) {
#pragma unroll
        for (int n = 0; n < NF; ++n) {
          int col = bn * BN + wc * (BN / 2) + n * 16 + lr;
          float vv = acc[m][n][i];
          if (bias) vv += bias[col];
          C[(size_t)row * ldc + col] = vv;
        }
      }
    }
  }
}

// ---------------------------------------------------------------------------
// K1 body: head-mean + row-normalize fold (one wave per (l,b,i) row).
// P[l,b,i,j] = (sum_h attn)/ (S_i + 12),  dvec = 12/(S_i+12)
// ---------------------------------------------------------------------------
__device__ __forceinline__ void k1_body(int rowblk,
                                        const float* __restrict__ attn,
                                        float* __restrict__ P,
                                        float* __restrict__ dvec) {
  int wid = threadIdx.x >> 6;
  int t   = threadIdx.x & 63;
  int row = rowblk * 4 + wid;              // lb*197 + i
  int i   = row % N1_;
  int lb  = row / N1_;
  const float* base = attn + (size_t)lb * (H_ * N1_ * N1_) + (size_t)i * N1_;
  float c0 = 0.f, c1 = 0.f, c2 = 0.f, c3 = 0.f;
#pragma unroll
  for (int h = 0; h < H_; ++h) {
    const float* p = base + (size_t)h * (N1_ * N1_);
    c0 += p[t];
    c1 += p[t + 64];
    c2 += p[t + 128];
    c3 += (t < 5) ? p[t + 192] : 0.f;
  }
  float rs = c0 + c1 + c2 + c3;
#pragma unroll
  for (int o = 32; o; o >>= 1) rs += __shfl_xor(rs, o);
  float inv = 1.f / (rs + 12.f);
  float* Pr = P + (size_t)row * N1_;
  Pr[t]       = c0 * inv;
  Pr[t + 64]  = c1 * inv;
  Pr[t + 128] = c2 * inv;
  if (t < 5) Pr[t + 192] = c3 * inv;
  if (t == 0) dvec[row] = 12.f * inv;
}

// ---------------------------------------------------------------------------
// MEGA kernel: blocks [0,600) = fused K/V projection GEMM (independent of k1),
// blocks [600, 600+18912) = k1 head-mean/normalize. The GEMM is L3-resident
// compute; k1 is the HBM stream — co-residency overlaps them.
// ---------------------------------------------------------------------------
__global__ __launch_bounds__(256) void mega_k1_kvgemm(const float* __restrict__ attn,
                                                      float* __restrict__ P,
                                                      float* __restrict__ dvec,
                                                      const float* __restrict__ x,
                                                      const float* __restrict__ k_w,
                                                      const float* __restrict__ v_w,
                                                      float* __restrict__ kvb) {
  int bid = blockIdx.x;
  if (bid < KV_GEMM_BLOCKS) {
    int bm = bid % 50, bn = bid / 50;
    gemm_body<128, 128, 4, 4>(bm, bn, x, (const int*)nullptr, k_w, v_w, 768,
                              (const float*)nullptr, kvb, B_ * N1_, D_, 1536);
  } else {
    k1_body(bid - KV_GEMM_BLOCKS, attn, P, dvec);
  }
}

// ---------------------------------------------------------------------------
// Standalone GEMM kernel for q (gathered) and proj.
// ---------------------------------------------------------------------------
template <int BM, int BN, int MF, int NF>
__global__ __launch_bounds__(256) void gemm_f32in(const float* __restrict__ A,
                                                  const int* __restrict__ gidx,
                                                  const float* __restrict__ W0,
                                                  const float* __restrict__ W1,
                                                  int nsplit,
                                                  const float* __restrict__ bias,
                                                  float* __restrict__ C,
                                                  int M, int K, int ldc) {
  gemm_body<BM, BN, MF, NF>(blockIdx.x, blockIdx.y, A, gidx, W0, W1, nsplit,
                            bias, C, M, K, ldc);
}

// ---------------------------------------------------------------------------
// K2: per-batch rollout chain (row 0 only) + top-k selection.
// ---------------------------------------------------------------------------
__global__ __launch_bounds__(512) void k2_chain_topk(const float* __restrict__ P,
                                                     const float* __restrict__ dvec,
                                                     int* __restrict__ gidx) {
  int b = blockIdx.x;
  __shared__ float v[N1_];
  __shared__ float part[2][N1_];
  int t    = threadIdx.x;        // 0..511
  int half = t >> 8;             // 0/1
  int j    = t & 255;            // column this thread owns (if <197)

  if (t < N1_) {
    const float* Pr = P + ((size_t)(11 * B_ + b) * N1_) * N1_;   // layer 11, row 0
    v[t] = Pr[t] + (t == 0 ? dvec[(11 * B_ + b) * N1_] : 0.f);
  }
  __syncthreads();

  for (int l = 10; l >= 0; --l) {
    if (j < N1_) {
      const float* Pc = P + ((size_t)(l * B_ + b) * N1_) * N1_ + j;
      float a[8] = {0.f, 0.f, 0.f, 0.f, 0.f, 0.f, 0.f, 0.f};
      int ibeg = half ? 96 : 0;
      int iend = half ? N1_ : 96;
      int i = ibeg;
      for (; i + 8 <= iend; i += 8) {
#pragma unroll
        for (int u = 0; u < 8; ++u)
          a[u] += v[i + u] * Pc[(size_t)(i + u) * N1_];
      }
      for (; i < iend; ++i) a[0] += v[i] * Pc[(size_t)i * N1_];
      float s = ((a[0] + a[1]) + (a[2] + a[3])) + ((a[4] + a[5]) + (a[6] + a[7]));
      if (half == 0) s += v[j] * dvec[(l * B_ + b) * N1_ + j];   // diagonal term once
      part[half][j] = s;
    }
    __syncthreads();
    if (t < N1_) v[t] = part[0][t] + part[1][t];
    __syncthreads();
  }

  // top-k over cls = v[1..196]; jax tie-break: value desc, index asc
  if (t < 64) {
    float val[4];
    int   idx[4];
#pragma unroll
    for (int c = 0; c < 4; ++c) {
      int n = t + c * 64;
      bool ok = (n < N1_ - 1);
      val[c] = ok ? v[n + 1] : -1e30f;
      idx[c] = ok ? n : (1 << 20);
    }
    for (int r = 0; r < R_; ++r) {
      float bv = val[0];
      int   bi = idx[0];
#pragma unroll
      for (int c = 1; c < 4; ++c)
        if (val[c] > bv || (val[c] == bv && idx[c] < bi)) { bv = val[c]; bi = idx[c]; }
#pragma unroll
      for (int o = 32; o; o >>= 1) {
        float ov = __shfl_xor(bv, o);
        int   oi = __shfl_xor(bi, o);
        if (ov > bv || (ov == bv && oi < bi)) { bv = ov; bi = oi; }
      }
      if (t == 0) gidx[b * R_ + r] = b * N1_ + bi + 1;
#pragma unroll
      for (int c = 0; c < 4; ++c)
        if (idx[c] == bi) val[c] = -1e30f;
    }
  }
}

// ---------------------------------------------------------------------------
// K5: per-(b,h) attention (f32).
// ---------------------------------------------------------------------------
__global__ __launch_bounds__(256) void k5_attn(const float* __restrict__ kvb,
                                               const float* __restrict__ qb,
                                               float* __restrict__ ctx) {
  int bh = blockIdx.x;
  int b = bh / H_, h = bh % H_;
  __shared__ float ks[N1_][68];
  __shared__ float qs[R_][64];
  __shared__ float sc[R_][200];
  __shared__ float rsum[R_];
  int t = threadIdx.x;
  int lane = t & 63, wid = t >> 6;

  const float* kbase = kvb + (size_t)b * N1_ * 1536 + h * 64;       // k half
  for (int n = wid; n < N1_; n += 4)
    ks[n][lane] = kbase[(size_t)n * 1536 + lane];
  const float* qrow = qb + (size_t)b * R_ * D_ + h * 64;
  for (int e = t; e < R_ * 64; e += 256) {
    int r = e >> 6, d = e & 63;
    qs[r][d] = qrow[(size_t)r * D_ + d];
  }
  __syncthreads();

  if (t < N1_) {
    float accr[R_];
#pragma unroll
    for (int r = 0; r < R_; ++r) accr[r] = 0.f;
#pragma unroll
    for (int d0 = 0; d0 < 4; ++d0) {
      float4 k0 = *(const float4*)&ks[t][d0 * 16 + 0];
      float4 k1 = *(const float4*)&ks[t][d0 * 16 + 4];
      float4 k2 = *(const float4*)&ks[t][d0 * 16 + 8];
      float4 k3 = *(const float4*)&ks[t][d0 * 16 + 12];
#pragma unroll
      for (int r = 0; r < R_; ++r) {
        float4 q0 = *(const float4*)&qs[r][d0 * 16 + 0];
        float4 q1 = *(const float4*)&qs[r][d0 * 16 + 4];
        float4 q2 = *(const float4*)&qs[r][d0 * 16 + 8];
        float4 q3 = *(const float4*)&qs[r][d0 * 16 + 12];
        accr[r] += k0.x * q0.x + k0.y * q0.y + k0.z * q0.z + k0.w * q0.w
                 + k1.x * q1.x + k1.y * q1.y + k1.z * q1.z + k1.w * q1.w
                 + k2.x * q2.x + k2.y * q2.y + k2.z * q2.z + k2.w * q2.w
                 + k3.x * q3.x + k3.y * q3.y + k3.z * q3.z + k3.w * q3.w;
      }
    }
#pragma unroll
    for (int r = 0; r < R_; ++r) sc[r][t] = accr[r] * 0.125f;
  }
  __syncthreads();

  for (int r = wid; r < R_; r += 4) {
    float x0 = sc[r][lane];
    float x1 = sc[r][lane + 64];
    float x2 = sc[r][lane + 128];
    bool ok3 = (lane + 192 < N1_);
    float x3 = ok3 ? sc[r][lane + 192] : -1e30f;
    float m = fmaxf(fmaxf(x0, x1), fmaxf(x2, x3));
#pragma unroll
    for (int o = 32; o; o >>= 1) m = fmaxf(m, __shfl_xor(m, o));
    float e0 = expf(x0 - m), e1 = expf(x1 - m), e2 = expf(x2 - m);
    float e3 = ok3 ? expf(x3 - m) : 0.f;
    float s = e0 + e1 + e2 + e3;
#pragma unroll
    for (int o = 32; o; o >>= 1) s += __shfl_xor(s, o);
    sc[r][lane] = e0; sc[r][lane + 64] = e1; sc[r][lane + 128] = e2;
    if (ok3) sc[r][lane + 192] = e3;
    if (lane == 0) rsum[r] = s;
  }
  __syncthreads();

  const float* vb = kvb + (size_t)b * N1_ * 1536 + 768 + h * 64 + lane;
  int r0 = wid, r1 = wid + 4, r2 = wid + 8, r3 = wid + 12, r4 = wid + 16;
  bool has4 = (r4 < R_);
  float a0 = 0.f, a1 = 0.f, a2 = 0.f, a3 = 0.f, a4 = 0.f;
  for (int n = 0; n < N1_; ++n) {
    float vv = vb[(size_t)n * 1536];
    a0 += sc[r0][n] * vv;
    a1 += sc[r1][n] * vv;
    a2 += sc[r2][n] * vv;
    a3 += sc[r3][n] * vv;
    if (has4) a4 += sc[r4][n] * vv;
  }
  float* cb = ctx + (size_t)(b * R_) * D_ + h * 64 + lane;
  cb[(size_t)r0 * D_] = a0 / rsum[r0];
  cb[(size_t)r1 * D_] = a1 / rsum[r1];
  cb[(size_t)r2 * D_] = a2 / rsum[r2];
  cb[(size_t)r3 * D_] = a3 / rsum[r3];
  if (has4) cb[(size_t)r4 * D_] = a4 / rsum[r4];
}

// ---------------------------------------------------------------------------
extern "C" void kernel_launch(void* const* d_in, const int* in_sizes, int n_in,
                              void* d_out, int out_size, void* d_ws, size_t ws_size,
                              hipStream_t stream) {
  const float* x      = (const float*)d_in[0];
  const float* attn   = (const float*)d_in[1];
  const float* q_w    = (const float*)d_in[2];
  const float* k_w    = (const float*)d_in[3];
  const float* v_w    = (const float*)d_in[4];
  const float* proj_w = (const float*)d_in[5];
  const float* proj_b = (const float*)d_in[6];
  float* out = (float*)d_out;

  // workspace layout (256B aligned segments)
  char* w = (char*)d_ws;
  auto take = [&](size_t bytes) { char* p = w; w += (bytes + 255) & ~(size_t)255; return p; };
  float* P    = (float*)take((size_t)L_ * B_ * N1_ * N1_ * 4);   // 59.6 MB
  float* dvec = (float*)take((size_t)L_ * B_ * N1_ * 4);
  int*   gidx = (int*)take(B_ * R_ * 4);
  float* kvb  = (float*)take((size_t)B_ * N1_ * 1536 * 4);       // 38.7 MB
  float* qbuf = (float*)take((size_t)B_ * R_ * D_ * 4);
  float* ctx  = (float*)take((size_t)B_ * R_ * D_ * 4);

  // 1) MEGA: k1 head-mean/normalize (HBM stream, 715MB) overlapped with the
  //    K/V projection GEMM (L3-resident MFMA compute) in one launch.
  hipLaunchKernelGGL(mega_k1_kvgemm, dim3(KV_GEMM_BLOCKS + K1_BLOCKS), dim3(256),
                     0, stream, attn, P, dvec, x, k_w, v_w, kvb);
  // 2) rollout chain (row 0) + top-19 indices (P is L2/L3-warm)
  hipLaunchKernelGGL(k2_chain_topk, dim3(B_), dim3(512), 0, stream, P, dvec, gidx);
  // 3) q projection of gathered top-R tokens
  hipLaunchKernelGGL((gemm_f32in<64, 64, 2, 2>), dim3(10, 12), dim3(256), 0, stream,
                     x, gidx, q_w, q_w, 1 << 30, (const float*)nullptr,
                     qbuf, B_ * R_, D_, D_);
  // 4) attention per (b,h)
  hipLaunchKernelGGL(k5_attn, dim3(B_ * H_), dim3(256), 0, stream, kvb, qbuf, ctx);
  // 5) output projection + bias -> d_out
  hipLaunchKernelGGL((gemm_f32in<64, 64, 2, 2>), dim3(10, 12), dim3(256), 0, stream,
                     ctx, (const int*)nullptr, proj_w, proj_w, 1 << 30, proj_b,
                     out, B_ * R_, D_, D_);
}